// Round 9
// baseline (86.053 us; speedup 1.0000x reference)
//
#include <hip/hip_runtime.h>

#define B 8
#define N 256
#define H 128
#define NF 6
#define EF 15
#define TD 4
#define FH 64
#define M (B*N)

typedef unsigned short u16;
using short8  = __attribute__((ext_vector_type(8))) short;
using short4v = __attribute__((ext_vector_type(4))) short;
using f32x4   = __attribute__((ext_vector_type(4))) float;

__device__ __forceinline__ u16 f2bf(float x) {
    unsigned u = __float_as_uint(x);
    u += 0x7fffu + ((u >> 16) & 1u);
    return (u16)(u >> 16);
}
__device__ __forceinline__ float bf2f(u16 h) {
    return __uint_as_float(((unsigned)h) << 16);
}

// Depth-2 staging pipeline (proven R6).
#define PIPE(NC, LDM, CMP)                          \
    LDM(0, pA0, pA1);                               \
    LDM(1, pB0, pB1);                               \
    WRX(0, pA0, pA1);                               \
    __syncthreads();                                \
    _Pragma("unroll")                               \
    for (int c = 0; c < (NC); c += 2) {             \
        WRX(1, pB0, pB1);                           \
        if (c + 2 < (NC)) LDM(c + 2, pA0, pA1);     \
        CMP(c, 0);                                  \
        __syncthreads();                            \
        if (c + 2 < (NC)) WRX(0, pA0, pA1);         \
        if (c + 3 < (NC)) LDM(c + 3, pB0, pB1);     \
        CMP(c + 1, 1);                              \
        __syncthreads();                            \
    }

// Common per-kernel thread indexing (256 thr = 4 waves):
//   wave w -> cols [16w,16w+16) of this block's 64-col slice
//   staging: sp = plane (hi/lo), sh = row 0..63, sseg = 16-k segment
#define IDX_COMMON                                          \
    const int t = threadIdx.x;                              \
    const int wave = t >> 6, lane = t & 63;                 \
    const int lrow = lane & 15;                             \
    const int kg8  = (lane >> 4) * 8;                       \
    const int rb   = (lane >> 4) * 4;                       \
    const int cb   = wave * 16;                             \
    const int sp = t >> 7, task = t & 127;                  \
    const int sh = task >> 1, sseg = (task & 1) * 16;

#define WRX(buf, q0, q1)                                    \
    { *(short8*)&sbt[buf][sp][sh][sseg] = q0;               \
      *(short8*)&sbt[buf][sp][sh][sseg + 8] = q1; }

// ---------------------------------------------------------------------------
// k_setup: unchanged from R6 (proven). grid 3072, 256 thr.
__global__ __launch_bounds__(256) void k_setup(
    const float* __restrict__ edge, const int* __restrict__ adj,
    const float* __restrict__ nf, const float* __restrict__ Wemb,
    const float* __restrict__ bemb,
    const float* __restrict__ msg_W, const float* __restrict__ upd_W,
    const float* __restrict__ W1,
    float* __restrict__ e0p, float* __restrict__ e1p, float* __restrict__ e2p,
    float* __restrict__ rp0, float* __restrict__ rp1, float* __restrict__ rp2,
    float* __restrict__ deg,
    u16* __restrict__ WeTh, u16* __restrict__ WeTl,
    u16* __restrict__ UwTh, u16* __restrict__ UwTl,
    u16* __restrict__ W1Th, u16* __restrict__ W1Tl,
    u16* __restrict__ eRh, u16* __restrict__ eRl,
    u16* __restrict__ eTh, u16* __restrict__ eTl)
{
    __shared__ __align__(16) float smem[3848];
    __shared__ float red[4];
    const int t = threadIdx.x;
    const int blk = blockIdx.x;

    if (blk < 2048) {
        const int i = blk & 255;
        const float* src = edge + (size_t)blk * (N * EF);
        float4* s4 = (float4*)smem;
#pragma unroll
        for (int u = 0; u < 4; ++u) {
            int idx = t + u * 256;
            if (idx < (N * EF) / 4) s4[idx] = *(const float4*)(src + idx * 4);
        }
        __syncthreads();
        const int j = t;
        float e0 = smem[j * EF + 12];
        float e1 = smem[j * EF + 13];
        float e2 = smem[j * EF + 14];
        size_t base = (size_t)blk * N + j;
        e0p[base] = e0; e1p[base] = e1; e2p[base] = e2;
        float m = (adj[j * N + i] > 0) ? 1.f : 0.f;
        rp0[base] = m * e0; rp1[base] = m * e1; rp2[base] = m * e2;
    } else if (blk < 2688) {
        int idx = (blk - 2048) * 256 + t;
        float v; u16 *dh, *dl; int d;
        if (idx < 3 * 16384) {
            int l = idx / 16384, r = idx & 16383;
            int c = r >> 7, h = r & 127;
            v = msg_W[l * ((H + 3) * H) + h * H + c];
            dh = WeTh; dl = WeTl; d = idx;
        } else if (idx < 3 * 16384 + 3 * 32768) {
            int r0 = idx - 3 * 16384;
            int l = r0 / 32768, r = r0 & 32767;
            int c = r >> 8, k = r & 255;
            v = upd_W[l * (2 * H * H) + k * H + c];
            dh = UwTh; dl = UwTl; d = r0;
        } else {
            int r0 = idx - 3 * 16384 - 3 * 32768;
            int f = r0 >> 8, k = r0 & 255;
            v = W1[k * FH + f];
            dh = W1Th; dl = W1Tl; d = r0;
        }
        u16 h = f2bf(v);
        dh[d] = h;
        dl[d] = f2bf(v - bf2f(h));
    } else if (blk < 2816) {
        int tile = blk - 2688;
        float (*sout)[132] = (float(*)[132])smem;
        {
            int row = t >> 4, h0 = (t & 15) * 8;
            int gr = tile * 16 + row;
            float xv[NF];
#pragma unroll
            for (int k = 0; k < NF; ++k) xv[k] = nf[gr * NF + k];
#pragma unroll
            for (int c = 0; c < 8; ++c) {
                float a = bemb[h0 + c];
#pragma unroll
                for (int k = 0; k < NF; ++k) a += xv[k] * Wemb[k * H + h0 + c];
                sout[row][h0 + c] = fmaxf(a, 0.f);
            }
        }
        __syncthreads();
        {
            int row = t >> 4, h0 = (t & 15) * 8;
            int gr = tile * 16 + row;
            short8 ph, pl;
#pragma unroll
            for (int c = 0; c < 8; ++c) {
                float x = sout[row][h0 + c];
                u16 h = f2bf(x);
                ph[c] = (short)h;
                pl[c] = (short)f2bf(x - bf2f(h));
            }
            *(short8*)&eRh[(size_t)gr * H + h0] = ph;
            *(short8*)&eRl[(size_t)gr * H + h0] = pl;
        }
        {
            int hh = t >> 1, jj = (t & 1) * 8;
            short8 th, tl;
#pragma unroll
            for (int r = 0; r < 8; ++r) {
                float x = sout[jj + r][hh];
                u16 h = f2bf(x);
                th[r] = (short)h;
                tl[r] = (short)f2bf(x - bf2f(h));
            }
            size_t o = (size_t)(tile >> 4) * H * N + (size_t)hh * N + ((tile & 15) * 16) + jj;
            *(short8*)&eTh[o] = th;
            *(short8*)&eTl[o] = tl;
        }
    } else {
        int jr = blk - 2816;
        float v = (adj[jr * N + t] > 0) ? 1.f : 0.f;
        for (int o = 32; o > 0; o >>= 1) v += __shfl_down(v, o);
        if ((t & 63) == 0) red[t >> 6] = v;
        __syncthreads();
        if (t == 0) deg[jr] = red[0] + red[1] + red[2] + red[3];
    }
}

// ---------------------------------------------------------------------------
// k_aggr: agg[j, colslice] = mask @ embT.  grid 256 = (b, tile, ch), 256 thr.
template <bool FIRST>
__global__ __launch_bounds__(256) void k_aggr(
    const u16* __restrict__ embT_hi, const u16* __restrict__ embT_lo,
    const int* __restrict__ adj,
    const float* __restrict__ rp0, const float* __restrict__ rp1,
    const float* __restrict__ rp2, float* __restrict__ ragg,
    u16* __restrict__ agg_hi, u16* __restrict__ agg_lo)
{
    __shared__ __align__(16) u16 sbt[2][2][64][40];
    __shared__ __align__(16) u16 smask[16][264];
    IDX_COMMON
    const int blk = blockIdx.x;
    const int b = blk >> 5, tile = (blk >> 1) & 15, ch = blk & 1;
    const int j0 = tile * 16, gb = b * N;
    short8 pA0, pA1, pB0, pB1;

    {   // stage mask rows (exact bf16 0/1): 16 rows x 256 i
        int row = t >> 4, i0 = (t & 15) * 16;
        const int* ap = adj + (j0 + row) * N + i0;
        int4 a0 = *(const int4*)(ap + 0),  a1 = *(const int4*)(ap + 4);
        int4 a2 = *(const int4*)(ap + 8),  a3 = *(const int4*)(ap + 12);
        short8 m0, m1;
        m0[0] = (a0.x > 0) ? (short)0x3F80 : (short)0;
        m0[1] = (a0.y > 0) ? (short)0x3F80 : (short)0;
        m0[2] = (a0.z > 0) ? (short)0x3F80 : (short)0;
        m0[3] = (a0.w > 0) ? (short)0x3F80 : (short)0;
        m0[4] = (a1.x > 0) ? (short)0x3F80 : (short)0;
        m0[5] = (a1.y > 0) ? (short)0x3F80 : (short)0;
        m0[6] = (a1.z > 0) ? (short)0x3F80 : (short)0;
        m0[7] = (a1.w > 0) ? (short)0x3F80 : (short)0;
        m1[0] = (a2.x > 0) ? (short)0x3F80 : (short)0;
        m1[1] = (a2.y > 0) ? (short)0x3F80 : (short)0;
        m1[2] = (a2.z > 0) ? (short)0x3F80 : (short)0;
        m1[3] = (a2.w > 0) ? (short)0x3F80 : (short)0;
        m1[4] = (a3.x > 0) ? (short)0x3F80 : (short)0;
        m1[5] = (a3.y > 0) ? (short)0x3F80 : (short)0;
        m1[6] = (a3.z > 0) ? (short)0x3F80 : (short)0;
        m1[7] = (a3.w > 0) ? (short)0x3F80 : (short)0;
        *(short8*)&smask[row][i0] = m0;
        *(short8*)&smask[row][i0 + 8] = m1;
    }

    if constexpr (FIRST) {
        if (ch == 0) {   // rp -> ragg reduction (published for all layers)
            int j16 = t >> 4, ic = t & 15;
            int gj = gb + j0 + j16;
            float s0 = 0.f, s1 = 0.f, s2 = 0.f;
#pragma unroll
            for (int k = 0; k < 16; ++k) {
                size_t o = ((size_t)(gb + ic * 16 + k)) * N + (j0 + j16);
                s0 += rp0[o]; s1 += rp1[o]; s2 += rp2[o];
            }
            for (int o = 8; o > 0; o >>= 1) {
                s0 += __shfl_down(s0, o, 16);
                s1 += __shfl_down(s1, o, 16);
                s2 += __shfl_down(s2, o, 16);
            }
            if (ic == 0) {
                float* rg = ragg + (size_t)gj * 3;
                rg[0] = s0; rg[1] = s1; rg[2] = s2;
            }
        }
    }

    const u16* sHi = embT_hi + (size_t)b * H * N + (size_t)(ch * 64) * N;
    const u16* sLo = embT_lo + (size_t)b * H * N + (size_t)(ch * 64) * N;
#define LDK(c, q0, q1)                                                   \
    { const u16* s_ = sp ? sLo : sHi;                                    \
      q0 = *(const short8*)(s_ + (size_t)sh * N + (c) * 32 + sseg);      \
      q1 = *(const short8*)(s_ + (size_t)sh * N + (c) * 32 + sseg + 8); }
#define CMPA(c, buf)                                                        \
    { short8 am = *(const short8*)&smask[lrow][(c) * 32 + kg8];             \
      short8 bh = *(const short8*)&sbt[buf][0][cb + lrow][kg8];             \
      short8 bl = *(const short8*)&sbt[buf][1][cb + lrow][kg8];             \
      acc = __builtin_amdgcn_mfma_f32_16x16x32_bf16(am, bh, acc, 0, 0, 0);  \
      acc = __builtin_amdgcn_mfma_f32_16x16x32_bf16(am, bl, acc, 0, 0, 0); }

    f32x4 acc = {0.f, 0.f, 0.f, 0.f};
    PIPE(8, LDK, CMPA)
#undef LDK
#undef CMPA

    const int col = ch * 64 + cb + lrow;
#pragma unroll
    for (int r = 0; r < 4; ++r) {
        float v = acc[r];
        u16 h = f2bf(v);
        size_t o = (size_t)(gb + j0 + rb + r) * H + col;
        agg_hi[o] = h;
        agg_lo[o] = f2bf(v - bf2f(h));
    }
}

// ---------------------------------------------------------------------------
// k_msgk: msg[j, colslice] = agg @ We + ragg@Wr + deg*mb.  grid 256, 256 thr.
__global__ __launch_bounds__(256) void k_msgk(
    const u16* __restrict__ agg_hi, const u16* __restrict__ agg_lo,
    const u16* __restrict__ WeT_hi, const u16* __restrict__ WeT_lo,
    const float* __restrict__ mwl, const float* __restrict__ mbl,
    const float* __restrict__ ragg, const float* __restrict__ deg,
    u16* __restrict__ msg_hi, u16* __restrict__ msg_lo)
{
    __shared__ __align__(16) u16 sbt[2][2][64][40];
    __shared__ __align__(16) u16 sa_hi[16][136], sa_lo[16][136];
    IDX_COMMON
    const int blk = blockIdx.x;
    const int b = blk >> 5, tile = (blk >> 1) & 15, ch = blk & 1;
    const int j0 = tile * 16, gb = b * N;
    short8 pA0, pA1, pB0, pB1;

    {   // stage agg rows (16 x 128, hi+lo)
        int row = t >> 4, k0 = (t & 15) * 8;
        size_t o = (size_t)(gb + j0 + row) * H + k0;
        *(short8*)&sa_hi[row][k0] = *(const short8*)&agg_hi[o];
        *(short8*)&sa_lo[row][k0] = *(const short8*)&agg_lo[o];
    }

    const u16* sHi = WeT_hi + (size_t)(ch * 64) * H;
    const u16* sLo = WeT_lo + (size_t)(ch * 64) * H;
#define LDK(c, q0, q1)                                                   \
    { const u16* s_ = sp ? sLo : sHi;                                    \
      q0 = *(const short8*)(s_ + (size_t)sh * H + (c) * 32 + sseg);      \
      q1 = *(const short8*)(s_ + (size_t)sh * H + (c) * 32 + sseg + 8); }
#define CMPB(c, buf)                                                        \
    { short8 ah = *(const short8*)&sa_hi[lrow][(c) * 32 + kg8];             \
      short8 al = *(const short8*)&sa_lo[lrow][(c) * 32 + kg8];             \
      short8 bh = *(const short8*)&sbt[buf][0][cb + lrow][kg8];             \
      short8 bl = *(const short8*)&sbt[buf][1][cb + lrow][kg8];             \
      acc = __builtin_amdgcn_mfma_f32_16x16x32_bf16(ah, bh, acc, 0, 0, 0);  \
      acc = __builtin_amdgcn_mfma_f32_16x16x32_bf16(ah, bl, acc, 0, 0, 0);  \
      acc = __builtin_amdgcn_mfma_f32_16x16x32_bf16(al, bh, acc, 0, 0, 0); }

    f32x4 acc = {0.f, 0.f, 0.f, 0.f};
    PIPE(4, LDK, CMPB)
#undef LDK
#undef CMPB

    const int hp = ch * 64 + cb + lrow;
    float w0 = mwl[(H + 0) * H + hp];
    float w1 = mwl[(H + 1) * H + hp];
    float w2 = mwl[(H + 2) * H + hp];
    float mb = mbl[hp];
#pragma unroll
    for (int r = 0; r < 4; ++r) {
        int jl = j0 + rb + r;
        const float* ra = ragg + (size_t)(gb + jl) * 3;
        float v = acc[r] + deg[jl] * mb + ra[0] * w0 + ra[1] * w1 + ra[2] * w2;
        u16 h = f2bf(v);
        size_t o = (size_t)(gb + jl) * H + hp;
        msg_hi[o] = h;
        msg_lo[o] = f2bf(v - bf2f(h));
    }
}

// ---------------------------------------------------------------------------
// k_updk: out[j, colslice] = relu([emb,msg] @ updW + ub).  grid 256, 256 thr.
// !LAST: writes row-major + transposed bf16 hi/lo.  LAST: row-major only.
template <bool LAST>
__global__ __launch_bounds__(256) void k_updk(
    const u16* __restrict__ embR_hi, const u16* __restrict__ embR_lo,
    const u16* __restrict__ msg_hi, const u16* __restrict__ msg_lo,
    const u16* __restrict__ UwT_hi, const u16* __restrict__ UwT_lo,
    const float* __restrict__ ubl,
    u16* __restrict__ oR_hi, u16* __restrict__ oR_lo,
    u16* __restrict__ oT_hi, u16* __restrict__ oT_lo)
{
    __shared__ __align__(16) u16 sbt[2][2][64][40];
    __shared__ __align__(16) u16 se_hi[16][136], se_lo[16][136];
    __shared__ __align__(16) u16 sm_hi[16][136], sm_lo[16][136];
    IDX_COMMON
    const int blk = blockIdx.x;
    const int b = blk >> 5, tile = (blk >> 1) & 15, ch = blk & 1;
    const int j0 = tile * 16, gb = b * N;
    short8 pA0, pA1, pB0, pB1;

    {   // stage emb + msg rows (16 x 128 each, hi+lo)
        int row = t >> 4, k0 = (t & 15) * 8;
        size_t o = (size_t)(gb + j0 + row) * H + k0;
        *(short8*)&se_hi[row][k0] = *(const short8*)&embR_hi[o];
        *(short8*)&se_lo[row][k0] = *(const short8*)&embR_lo[o];
        *(short8*)&sm_hi[row][k0] = *(const short8*)&msg_hi[o];
        *(short8*)&sm_lo[row][k0] = *(const short8*)&msg_lo[o];
    }

    const u16* sHi = UwT_hi + (size_t)(ch * 64) * (2 * H);
    const u16* sLo = UwT_lo + (size_t)(ch * 64) * (2 * H);
#define LDK(c, q0, q1)                                                         \
    { const u16* s_ = sp ? sLo : sHi;                                          \
      q0 = *(const short8*)(s_ + (size_t)sh * (2 * H) + (c) * 32 + sseg);      \
      q1 = *(const short8*)(s_ + (size_t)sh * (2 * H) + (c) * 32 + sseg + 8); }
#define CMPC(c, buf)                                                        \
    { int kc = ((c) & 3) * 32 + kg8; short8 ah, al;                         \
      if ((c) < 4) { ah = *(const short8*)&se_hi[lrow][kc];                 \
                     al = *(const short8*)&se_lo[lrow][kc]; }               \
      else         { ah = *(const short8*)&sm_hi[lrow][kc];                 \
                     al = *(const short8*)&sm_lo[lrow][kc]; }               \
      short8 bh = *(const short8*)&sbt[buf][0][cb + lrow][kg8];             \
      short8 bl = *(const short8*)&sbt[buf][1][cb + lrow][kg8];             \
      acc = __builtin_amdgcn_mfma_f32_16x16x32_bf16(ah, bh, acc, 0, 0, 0);  \
      acc = __builtin_amdgcn_mfma_f32_16x16x32_bf16(ah, bl, acc, 0, 0, 0);  \
      acc = __builtin_amdgcn_mfma_f32_16x16x32_bf16(al, bh, acc, 0, 0, 0); }

    f32x4 acc = {0.f, 0.f, 0.f, 0.f};
    PIPE(8, LDK, CMPC)
#undef LDK
#undef CMPC

    const int hp = ch * 64 + cb + lrow;
    const float ub = ubl[hp];
    short4v th, tl;
#pragma unroll
    for (int r = 0; r < 4; ++r) {
        float v = fmaxf(acc[r] + ub, 0.f);
        u16 h = f2bf(v);
        u16 l = f2bf(v - bf2f(h));
        size_t o = (size_t)(gb + j0 + rb + r) * H + hp;
        oR_hi[o] = h;
        oR_lo[o] = l;
        th[r] = (short)h;
        tl[r] = (short)l;
    }
    if constexpr (!LAST) {
        size_t o = (size_t)b * H * N + (size_t)hp * N + j0 + rb;
        *(short4v*)&oT_hi[o] = th;
        *(short4v*)&oT_lo[o] = tl;
    }
}

// ---------------------------------------------------------------------------
// k_hijk: hi/hj = out @ W1[:H]/W1[H:2H].  grid 256 = (b, tile, half), 256 thr.
__global__ __launch_bounds__(256) void k_hijk(
    const u16* __restrict__ outR_hi, const u16* __restrict__ outR_lo,
    const u16* __restrict__ W1T_hi, const u16* __restrict__ W1T_lo,
    float* __restrict__ hi_out, float* __restrict__ hj_out)
{
    __shared__ __align__(16) u16 sbt[2][2][64][40];
    __shared__ __align__(16) u16 so_hi[16][136], so_lo[16][136];
    IDX_COMMON
    const int blk = blockIdx.x;
    const int b = blk >> 5, tile = (blk >> 1) & 15, half = blk & 1;
    const int j0 = tile * 16, gb = b * N;
    short8 pA0, pA1, pB0, pB1;

    {   // stage out rows (16 x 128, hi+lo)
        int row = t >> 4, k0 = (t & 15) * 8;
        size_t o = (size_t)(gb + j0 + row) * H + k0;
        *(short8*)&so_hi[row][k0] = *(const short8*)&outR_hi[o];
        *(short8*)&so_lo[row][k0] = *(const short8*)&outR_lo[o];
    }

    const u16* sHi = W1T_hi + half * 128;
    const u16* sLo = W1T_lo + half * 128;
#define LDK(c, q0, q1)                                                    \
    { const u16* s_ = sp ? sLo : sHi;                                     \
      q0 = *(const short8*)(s_ + (size_t)sh * 256 + (c) * 32 + sseg);     \
      q1 = *(const short8*)(s_ + (size_t)sh * 256 + (c) * 32 + sseg + 8); }
#define CMPD(c, buf)                                                        \
    { short8 ah = *(const short8*)&so_hi[lrow][(c) * 32 + kg8];             \
      short8 al = *(const short8*)&so_lo[lrow][(c) * 32 + kg8];             \
      short8 bh = *(const short8*)&sbt[buf][0][cb + lrow][kg8];             \
      short8 bl = *(const short8*)&sbt[buf][1][cb + lrow][kg8];             \
      acc = __builtin_amdgcn_mfma_f32_16x16x32_bf16(ah, bh, acc, 0, 0, 0);  \
      acc = __builtin_amdgcn_mfma_f32_16x16x32_bf16(ah, bl, acc, 0, 0, 0);  \
      acc = __builtin_amdgcn_mfma_f32_16x16x32_bf16(al, bh, acc, 0, 0, 0); }

    f32x4 acc = {0.f, 0.f, 0.f, 0.f};
    PIPE(4, LDK, CMPD)
#undef LDK
#undef CMPD

    float* dst = half ? hj_out : hi_out;
    const int f = cb + lrow;
#pragma unroll
    for (int r = 0; r < 4; ++r)
        dst[(size_t)(gb + j0 + rb + r) * FH + f] = acc[r];
}

// ---------------------------------------------------------------------------
// k_final: unchanged from R6. grid 2048, 256 thr.
__global__ __launch_bounds__(256) void k_final(
    const float* __restrict__ hi, const float* __restrict__ hj,
    const float* __restrict__ e0p, const float* __restrict__ e1p,
    const float* __restrict__ e2p, const float* __restrict__ temporal,
    const float* __restrict__ W1, const float* __restrict__ b1,
    const float* __restrict__ W2, const float* __restrict__ b2,
    float* __restrict__ flows) {
    __shared__ float his[8][FH];
    __shared__ float hjs[32][FH + 2];
    __shared__ float wr0[FH], wr1[FH], wr2[FH];
    __shared__ float wt0[FH], wt1[FH], wt2[FH], wt3[FH], bb[FH], w2s[FH];
    int blk = blockIdx.x;
    int jt = blk & 7, it = (blk >> 3) & 31, b = blk >> 8;
    int tid = threadIdx.x;
#pragma unroll
    for (int u = 0; u < 2; ++u) {
        int idx = u * 256 + tid;
        his[idx >> 6][idx & 63] = hi[((size_t)(b * N) + it * 8 + (idx >> 6)) * FH + (idx & 63)];
    }
#pragma unroll
    for (int u = 0; u < 8; ++u) {
        int idx = u * 256 + tid;
        hjs[idx >> 6][idx & 63] = hj[((size_t)(b * N) + jt * 32 + (idx >> 6)) * FH + (idx & 63)];
    }
    {
        int f = tid & 63, g = tid >> 6;
        if (g == 0) { wr0[f] = W1[(2 * H + 0) * FH + f]; wt0[f] = W1[(2 * H + 3) * FH + f]; bb[f] = b1[f]; }
        if (g == 1) { wr1[f] = W1[(2 * H + 1) * FH + f]; wt1[f] = W1[(2 * H + 4) * FH + f]; w2s[f] = W2[f]; }
        if (g == 2) { wr2[f] = W1[(2 * H + 2) * FH + f]; wt2[f] = W1[(2 * H + 5) * FH + f]; }
        if (g == 3) { wt3[f] = W1[(2 * H + 6) * FH + f]; }
    }
    __syncthreads();
    int ti = tid >> 5, tj = tid & 31;
    int i = it * 8 + ti, j = jt * 32 + tj;
    size_t pij = ((size_t)(b * N) + i) * N + j;
    float e0 = e0p[pij], e1 = e1p[pij], e2 = e2p[pij];
    float4 tf = *(const float4*)(temporal + pij * TD);
    float acc = 0.f;
#pragma unroll 8
    for (int f = 0; f < FH; ++f) {
        float v = his[ti][f] + hjs[tj][f] + bb[f]
                + e0 * wr0[f] + e1 * wr1[f] + e2 * wr2[f]
                + tf.x * wt0[f] + tf.y * wt1[f] + tf.z * wt2[f] + tf.w * wt3[f];
        acc += fmaxf(v, 0.f) * w2s[f];
    }
    flows[pij] = fmaxf(acc + b2[0], 0.f);
}

// ---------------------------------------------------------------------------
extern "C" void kernel_launch(void* const* d_in, const int* in_sizes, int n_in,
                              void* d_out, int out_size, void* d_ws, size_t ws_size,
                              hipStream_t stream) {
    const float* nf       = (const float*)d_in[0];
    const float* edge     = (const float*)d_in[1];
    const float* temporal = (const float*)d_in[2];
    const int*   adj      = (const int*)d_in[3];
    const float* W_emb    = (const float*)d_in[4];
    const float* b_emb    = (const float*)d_in[5];
    const float* msg_W    = (const float*)d_in[6];
    const float* msg_b    = (const float*)d_in[7];
    const float* upd_W    = (const float*)d_in[8];
    const float* upd_b    = (const float*)d_in[9];
    const float* W1       = (const float*)d_in[10];
    const float* b1       = (const float*)d_in[11];
    const float* W2       = (const float*)d_in[12];
    const float* b2       = (const float*)d_in[13];
    float* out = (float*)d_out;
    (void)in_sizes; (void)n_in; (void)out_size; (void)ws_size;

    char* p = (char*)d_ws;
    auto take = [&](size_t bytes) { char* r = p; p += (bytes + 255) & ~(size_t)255; return r; };
    float* deg   = (float*)take(256 * 4);
    float* ragg  = (float*)take((size_t)M * 3 * 4);
    float* e0p   = (float*)take((size_t)B * N * N * 4);
    float* e1p   = (float*)take((size_t)B * N * N * 4);
    float* e2p   = (float*)take((size_t)B * N * N * 4);
    float* rp0   = (float*)take((size_t)B * N * N * 4);
    float* rp1   = (float*)take((size_t)B * N * N * 4);
    float* rp2   = (float*)take((size_t)B * N * N * 4);
    float* hi    = (float*)take((size_t)M * FH * 4);
    float* hj    = (float*)take((size_t)M * FH * 4);
    u16* eRhA = (u16*)take((size_t)M * H * 2);
    u16* eRlA = (u16*)take((size_t)M * H * 2);
    u16* eThA = (u16*)take((size_t)M * H * 2);
    u16* eTlA = (u16*)take((size_t)M * H * 2);
    u16* eRhB = (u16*)take((size_t)M * H * 2);
    u16* eRlB = (u16*)take((size_t)M * H * 2);
    u16* eThB = (u16*)take((size_t)M * H * 2);
    u16* eTlB = (u16*)take((size_t)M * H * 2);
    u16* aggH = (u16*)take((size_t)M * H * 2);
    u16* aggL = (u16*)take((size_t)M * H * 2);
    u16* msgH = (u16*)take((size_t)M * H * 2);
    u16* msgL = (u16*)take((size_t)M * H * 2);
    u16* WeTh = (u16*)take(3 * 16384 * 2);
    u16* WeTl = (u16*)take(3 * 16384 * 2);
    u16* UwTh = (u16*)take(3 * 32768 * 2);
    u16* UwTl = (u16*)take(3 * 32768 * 2);
    u16* W1Th = (u16*)take(16384 * 2);
    u16* W1Tl = (u16*)take(16384 * 2);

    k_setup<<<3072, 256, 0, stream>>>(edge, adj, nf, W_emb, b_emb,
                                      msg_W, upd_W, W1,
                                      e0p, e1p, e2p, rp0, rp1, rp2, deg,
                                      WeTh, WeTl, UwTh, UwTl, W1Th, W1Tl,
                                      eRhA, eRlA, eThA, eTlA);

    const int mwS = (H + 3) * H;
    // -------- layer 0 --------
    k_aggr<true><<<256, 256, 0, stream>>>(eThA, eTlA, adj, rp0, rp1, rp2, ragg,
                                          aggH, aggL);
    k_msgk<<<256, 256, 0, stream>>>(aggH, aggL, WeTh + 0 * 16384, WeTl + 0 * 16384,
                                    msg_W + 0 * mwS, msg_b + 0 * H, ragg, deg,
                                    msgH, msgL);
    k_updk<false><<<256, 256, 0, stream>>>(eRhA, eRlA, msgH, msgL,
                                           UwTh + 0 * 32768, UwTl + 0 * 32768,
                                           upd_b + 0 * H,
                                           eRhB, eRlB, eThB, eTlB);
    // -------- layer 1 --------
    k_aggr<false><<<256, 256, 0, stream>>>(eThB, eTlB, adj, rp0, rp1, rp2, ragg,
                                           aggH, aggL);
    k_msgk<<<256, 256, 0, stream>>>(aggH, aggL, WeTh + 1 * 16384, WeTl + 1 * 16384,
                                    msg_W + 1 * mwS, msg_b + 1 * H, ragg, deg,
                                    msgH, msgL);
    k_updk<false><<<256, 256, 0, stream>>>(eRhB, eRlB, msgH, msgL,
                                           UwTh + 1 * 32768, UwTl + 1 * 32768,
                                           upd_b + 1 * H,
                                           eRhA, eRlA, eThA, eTlA);
    // -------- layer 2 --------
    k_aggr<false><<<256, 256, 0, stream>>>(eThA, eTlA, adj, rp0, rp1, rp2, ragg,
                                           aggH, aggL);
    k_msgk<<<256, 256, 0, stream>>>(aggH, aggL, WeTh + 2 * 16384, WeTl + 2 * 16384,
                                    msg_W + 2 * mwS, msg_b + 2 * H, ragg, deg,
                                    msgH, msgL);
    k_updk<true><<<256, 256, 0, stream>>>(eRhA, eRlA, msgH, msgL,
                                          UwTh + 2 * 32768, UwTl + 2 * 32768,
                                          upd_b + 2 * H,
                                          eRhB, eRlB, eThB, eTlB);
    // -------- readout --------
    k_hijk<<<256, 256, 0, stream>>>(eRhB, eRlB, W1Th, W1Tl, hi, hj);
    k_final<<<2048, 256, 0, stream>>>(hi, hj, e0p, e1p, e2p, temporal,
                                      W1, b1, W2, b2, out);
}

// Round 10
// 83.823 us; speedup vs baseline: 1.0266x; 1.0266x over previous
//
#include <hip/hip_runtime.h>

#define B 8
#define N 256
#define H 128
#define NF 6
#define EF 15
#define TD 4
#define FH 64
#define M (B*N)

typedef unsigned short u16;
using short8  = __attribute__((ext_vector_type(8))) short;
using short4v = __attribute__((ext_vector_type(4))) short;
using f32x4   = __attribute__((ext_vector_type(4))) float;

__device__ __forceinline__ u16 f2bf(float x) {
    unsigned u = __float_as_uint(x);
    u += 0x7fffu + ((u >> 16) & 1u);
    return (u16)(u >> 16);
}
__device__ __forceinline__ float bf2f(u16 h) {
    return __uint_as_float(((unsigned)h) << 16);
}

// ---------------------------------------------------------------------------
// k_setup: unchanged from R6 (proven). grid 3072, 256 thr.
__global__ __launch_bounds__(256) void k_setup(
    const float* __restrict__ edge, const int* __restrict__ adj,
    const float* __restrict__ nf, const float* __restrict__ Wemb,
    const float* __restrict__ bemb,
    const float* __restrict__ msg_W, const float* __restrict__ upd_W,
    const float* __restrict__ W1,
    float* __restrict__ e0p, float* __restrict__ e1p, float* __restrict__ e2p,
    float* __restrict__ rp0, float* __restrict__ rp1, float* __restrict__ rp2,
    float* __restrict__ deg,
    u16* __restrict__ WeTh, u16* __restrict__ WeTl,
    u16* __restrict__ UwTh, u16* __restrict__ UwTl,
    u16* __restrict__ W1Th, u16* __restrict__ W1Tl,
    u16* __restrict__ eRh, u16* __restrict__ eRl,
    u16* __restrict__ eTh, u16* __restrict__ eTl)
{
    __shared__ __align__(16) float smem[3848];
    __shared__ float red[4];
    const int t = threadIdx.x;
    const int blk = blockIdx.x;

    if (blk < 2048) {
        const int i = blk & 255;
        const float* src = edge + (size_t)blk * (N * EF);
        float4* s4 = (float4*)smem;
#pragma unroll
        for (int u = 0; u < 4; ++u) {
            int idx = t + u * 256;
            if (idx < (N * EF) / 4) s4[idx] = *(const float4*)(src + idx * 4);
        }
        __syncthreads();
        const int j = t;
        float e0 = smem[j * EF + 12];
        float e1 = smem[j * EF + 13];
        float e2 = smem[j * EF + 14];
        size_t base = (size_t)blk * N + j;
        e0p[base] = e0; e1p[base] = e1; e2p[base] = e2;
        float m = (adj[j * N + i] > 0) ? 1.f : 0.f;
        rp0[base] = m * e0; rp1[base] = m * e1; rp2[base] = m * e2;
    } else if (blk < 2688) {
        int idx = (blk - 2048) * 256 + t;
        float v; u16 *dh, *dl; int d;
        if (idx < 3 * 16384) {
            int l = idx / 16384, r = idx & 16383;
            int c = r >> 7, h = r & 127;
            v = msg_W[l * ((H + 3) * H) + h * H + c];
            dh = WeTh; dl = WeTl; d = idx;
        } else if (idx < 3 * 16384 + 3 * 32768) {
            int r0 = idx - 3 * 16384;
            int l = r0 / 32768, r = r0 & 32767;
            int c = r >> 8, k = r & 255;
            v = upd_W[l * (2 * H * H) + k * H + c];
            dh = UwTh; dl = UwTl; d = r0;
        } else {
            int r0 = idx - 3 * 16384 - 3 * 32768;
            int f = r0 >> 8, k = r0 & 255;
            v = W1[k * FH + f];
            dh = W1Th; dl = W1Tl; d = r0;
        }
        u16 h = f2bf(v);
        dh[d] = h;
        dl[d] = f2bf(v - bf2f(h));
    } else if (blk < 2816) {
        int tile = blk - 2688;
        float (*sout)[132] = (float(*)[132])smem;
        {
            int row = t >> 4, h0 = (t & 15) * 8;
            int gr = tile * 16 + row;
            float xv[NF];
#pragma unroll
            for (int k = 0; k < NF; ++k) xv[k] = nf[gr * NF + k];
#pragma unroll
            for (int c = 0; c < 8; ++c) {
                float a = bemb[h0 + c];
#pragma unroll
                for (int k = 0; k < NF; ++k) a += xv[k] * Wemb[k * H + h0 + c];
                sout[row][h0 + c] = fmaxf(a, 0.f);
            }
        }
        __syncthreads();
        {
            int row = t >> 4, h0 = (t & 15) * 8;
            int gr = tile * 16 + row;
            short8 ph, pl;
#pragma unroll
            for (int c = 0; c < 8; ++c) {
                float x = sout[row][h0 + c];
                u16 h = f2bf(x);
                ph[c] = (short)h;
                pl[c] = (short)f2bf(x - bf2f(h));
            }
            *(short8*)&eRh[(size_t)gr * H + h0] = ph;
            *(short8*)&eRl[(size_t)gr * H + h0] = pl;
        }
        {
            int hh = t >> 1, jj = (t & 1) * 8;
            short8 th, tl;
#pragma unroll
            for (int r = 0; r < 8; ++r) {
                float x = sout[jj + r][hh];
                u16 h = f2bf(x);
                th[r] = (short)h;
                tl[r] = (short)f2bf(x - bf2f(h));
            }
            size_t o = (size_t)(tile >> 4) * H * N + (size_t)hh * N + ((tile & 15) * 16) + jj;
            *(short8*)&eTh[o] = th;
            *(short8*)&eTl[o] = tl;
        }
    } else {
        int jr = blk - 2816;
        float v = (adj[jr * N + t] > 0) ? 1.f : 0.f;
        for (int o = 32; o > 0; o >>= 1) v += __shfl_down(v, o);
        if ((t & 63) == 0) red[t >> 6] = v;
        __syncthreads();
        if (t == 0) deg[jr] = red[0] + red[1] + red[2] + red[3];
    }
}

// ---------------------------------------------------------------------------
// k_layer: MFMA bf16 hi/lo-split fused GNN layer, register-preloaded B-panels.
// grid 128 = (b, 16-node tile); 512 thr = 8 waves; wave w -> cols [16w,16w+16).
template <bool FIRST, bool LAST>
__global__ __launch_bounds__(512, 1) void k_layer(
    const u16* __restrict__ embR_hi, const u16* __restrict__ embR_lo,
    const u16* __restrict__ embT_hi, const u16* __restrict__ embT_lo,
    const int* __restrict__ adj,
    const float* __restrict__ rp0, const float* __restrict__ rp1,
    const float* __restrict__ rp2, float* __restrict__ ragg,
    const float* __restrict__ deg,
    const u16* __restrict__ WeT_hi, const u16* __restrict__ WeT_lo,
    const float* __restrict__ mwl, const float* __restrict__ mbl,
    const u16* __restrict__ UwT_hi, const u16* __restrict__ UwT_lo,
    const float* __restrict__ ubl,
    u16* __restrict__ oR_hi, u16* __restrict__ oR_lo,
    u16* __restrict__ oT_hi, u16* __restrict__ oT_lo,
    const u16* __restrict__ W1T_hi, const u16* __restrict__ W1T_lo,
    float* __restrict__ hi_out, float* __restrict__ hj_out)
{
    __shared__ __align__(16) u16 smask[16][264];
    __shared__ __align__(16) u16 semb_hi[16][136], semb_lo[16][136];
    __shared__ __align__(16) u16 sagg_hi[16][136], sagg_lo[16][136];
    __shared__ __align__(16) u16 smsg_hi[16][136], smsg_lo[16][136];
    __shared__ __align__(16) float sout[16][132];
    __shared__ float sragg[16][4];

    const int t = threadIdx.x;
    const int wave = t >> 6, lane = t & 63;
    const int lrow = lane & 15;
    const int kg8  = (lane >> 4) * 8;     // fragment k offset
    const int rb   = (lane >> 4) * 4;     // D row base (verified C/D layout)
    const int cb   = wave * 16;
    const int blk  = blockIdx.x;
    const int b    = blk >> 4, tile = blk & 15;
    const int j0   = tile * 16;
    const int gb   = b * N;

    // ---- entry staging: table loads FIRST (their waitcnt then won't drain
    //      the later-issued fragment loads) ---------------------------------
    {
        int j = t >> 5, i0 = (t & 31) * 8;
        int4 a0 = *(const int4*)(adj + (j0 + j) * N + i0);
        int4 a1 = *(const int4*)(adj + (j0 + j) * N + i0 + 4);
        short8 mrow;
        mrow[0] = (a0.x > 0) ? (short)0x3F80 : (short)0;
        mrow[1] = (a0.y > 0) ? (short)0x3F80 : (short)0;
        mrow[2] = (a0.z > 0) ? (short)0x3F80 : (short)0;
        mrow[3] = (a0.w > 0) ? (short)0x3F80 : (short)0;
        mrow[4] = (a1.x > 0) ? (short)0x3F80 : (short)0;
        mrow[5] = (a1.y > 0) ? (short)0x3F80 : (short)0;
        mrow[6] = (a1.z > 0) ? (short)0x3F80 : (short)0;
        mrow[7] = (a1.w > 0) ? (short)0x3F80 : (short)0;
        *(short8*)&smask[j][i0] = mrow;
        int h0 = (t & 31) * 4;
        *(short4v*)&semb_hi[j][h0] = *(const short4v*)&embR_hi[(size_t)(gb + j0 + j) * H + h0];
        *(short4v*)&semb_lo[j][h0] = *(const short4v*)&embR_lo[(size_t)(gb + j0 + j) * H + h0];
    }
    if constexpr (FIRST) {
        int j16 = t >> 5, ic = t & 31;
        int gj = gb + j0 + j16;
        float s0 = 0.f, s1 = 0.f, s2 = 0.f;
#pragma unroll
        for (int k = 0; k < 8; ++k) {
            size_t o = ((size_t)(gb + ic * 8 + k)) * N + (j0 + j16);
            s0 += rp0[o]; s1 += rp1[o]; s2 += rp2[o];
        }
        for (int o = 16; o > 0; o >>= 1) {
            s0 += __shfl_down(s0, o, 32);
            s1 += __shfl_down(s1, o, 32);
            s2 += __shfl_down(s2, o, 32);
        }
        if (ic == 0) {
            sragg[j16][0] = s0; sragg[j16][1] = s1; sragg[j16][2] = s2;
            float* rg = ragg + (size_t)gj * 3;
            rg[0] = s0; rg[1] = s1; rg[2] = s2;
        }
    } else {
        if (t < 48) sragg[t / 3][t % 3] = ragg[(size_t)(gb + j0 + t / 3) * 3 + (t % 3)];
    }

    // ---- hoisted B-panel fragment loads: A, B, C issued back-to-back ------
    short8 fa0[8], fa1[8], fb0[4], fb1[4], fc0[8], fc1[8];
    {
        const u16* pH = embT_hi + (size_t)b * H * N + (size_t)(cb + lrow) * N;
        const u16* pL = embT_lo + (size_t)b * H * N + (size_t)(cb + lrow) * N;
#pragma unroll
        for (int c = 0; c < 8; ++c) {
            fa0[c] = *(const short8*)(pH + c * 32 + kg8);
            fa1[c] = *(const short8*)(pL + c * 32 + kg8);
        }
    }
    {
        const u16* pH = WeT_hi + (size_t)(cb + lrow) * H;
        const u16* pL = WeT_lo + (size_t)(cb + lrow) * H;
#pragma unroll
        for (int c = 0; c < 4; ++c) {
            fb0[c] = *(const short8*)(pH + c * 32 + kg8);
            fb1[c] = *(const short8*)(pL + c * 32 + kg8);
        }
    }
    {
        const u16* pH = UwT_hi + (size_t)(cb + lrow) * (2 * H);
        const u16* pL = UwT_lo + (size_t)(cb + lrow) * (2 * H);
#pragma unroll
        for (int c = 0; c < 8; ++c) {
            fc0[c] = *(const short8*)(pH + c * 32 + kg8);
            fc1[c] = *(const short8*)(pL + c * 32 + kg8);
        }
    }
    __syncthreads();   // tables ready (drains frag loads too: ONE latency)

    // ================= Phase A: agg = mask @ emb  (K=256) ==================
    f32x4 acc = {0.f, 0.f, 0.f, 0.f};
#pragma unroll
    for (int c = 0; c < 8; ++c) {
        short8 am = *(const short8*)&smask[lrow][c * 32 + kg8];
        acc = __builtin_amdgcn_mfma_f32_16x16x32_bf16(am, fa0[c], acc, 0, 0, 0);
        acc = __builtin_amdgcn_mfma_f32_16x16x32_bf16(am, fa1[c], acc, 0, 0, 0);
    }
#pragma unroll
    for (int r = 0; r < 4; ++r) {
        float v = acc[r];
        u16 h = f2bf(v);
        sagg_hi[rb + r][cb + lrow] = h;
        sagg_lo[rb + r][cb + lrow] = f2bf(v - bf2f(h));
    }
    __syncthreads();   // sagg ready

    // ========== Phase B: msg = agg @ We + ragg@Wr + deg*mb  (K=128) ========
    acc = (f32x4){0.f, 0.f, 0.f, 0.f};
#pragma unroll
    for (int c = 0; c < 4; ++c) {
        short8 ah = *(const short8*)&sagg_hi[lrow][c * 32 + kg8];
        short8 al = *(const short8*)&sagg_lo[lrow][c * 32 + kg8];
        acc = __builtin_amdgcn_mfma_f32_16x16x32_bf16(ah, fb0[c], acc, 0, 0, 0);
        acc = __builtin_amdgcn_mfma_f32_16x16x32_bf16(ah, fb1[c], acc, 0, 0, 0);
        acc = __builtin_amdgcn_mfma_f32_16x16x32_bf16(al, fb0[c], acc, 0, 0, 0);
    }
    {
        int hp = cb + lrow;
        float w0 = mwl[(H + 0) * H + hp];
        float w1 = mwl[(H + 1) * H + hp];
        float w2 = mwl[(H + 2) * H + hp];
        float mb = mbl[hp];
#pragma unroll
        for (int r = 0; r < 4; ++r) {
            int jl = j0 + rb + r;
            float v = acc[r] + deg[jl] * mb
                    + sragg[rb + r][0] * w0 + sragg[rb + r][1] * w1
                    + sragg[rb + r][2] * w2;
            u16 h = f2bf(v);
            smsg_hi[rb + r][hp] = h;
            smsg_lo[rb + r][hp] = f2bf(v - bf2f(h));
        }
    }
    __syncthreads();   // smsg ready

    // ====== Phase C: out = relu([emb,msg] @ updW + ub)  (K=256) ============
    // (LAST: issue phase-D fragment loads now; drained at the C-end barrier,
    //  with all of phase C as slack.)
    short8 fd0[4], fd1[4];
    const int fD   = (wave & 3) * 16 + lrow;
    const int koD  = (wave >= 4) ? 128 : 0;
    const int colD = ((wave >= 4) ? 64 : 0) + fD;
    if constexpr (LAST) {
        const u16* pH = W1T_hi + (size_t)fD * 256 + koD;
        const u16* pL = W1T_lo + (size_t)fD * 256 + koD;
#pragma unroll
        for (int c = 0; c < 4; ++c) {
            fd0[c] = *(const short8*)(pH + c * 32 + kg8);
            fd1[c] = *(const short8*)(pL + c * 32 + kg8);
        }
    }
    acc = (f32x4){0.f, 0.f, 0.f, 0.f};
#pragma unroll
    for (int c = 0; c < 8; ++c) {
        int kc = (c & 3) * 32 + kg8;
        short8 ah, al;
        if (c < 4) {
            ah = *(const short8*)&semb_hi[lrow][kc];
            al = *(const short8*)&semb_lo[lrow][kc];
        } else {
            ah = *(const short8*)&smsg_hi[lrow][kc];
            al = *(const short8*)&smsg_lo[lrow][kc];
        }
        acc = __builtin_amdgcn_mfma_f32_16x16x32_bf16(ah, fc0[c], acc, 0, 0, 0);
        acc = __builtin_amdgcn_mfma_f32_16x16x32_bf16(ah, fc1[c], acc, 0, 0, 0);
        acc = __builtin_amdgcn_mfma_f32_16x16x32_bf16(al, fc0[c], acc, 0, 0, 0);
    }
    {
        float ub = ubl[cb + lrow];
#pragma unroll
        for (int r = 0; r < 4; ++r) {
            float v = fmaxf(acc[r] + ub, 0.f);
            if constexpr (LAST) {
                u16 h = f2bf(v);
                sagg_hi[rb + r][cb + lrow] = h;
                sagg_lo[rb + r][cb + lrow] = f2bf(v - bf2f(h));
            } else {
                sout[rb + r][cb + lrow] = v;
            }
        }
    }
    __syncthreads();   // sout / sagg(out) ready

    if constexpr (!LAST) {
        {   // row-major bf16 hi/lo out
            int row = t >> 5, h0 = (t & 31) * 4;
            int gr = gb + j0 + row;
            float4 v = *(const float4*)&sout[row][h0];
            float xs[4] = {v.x, v.y, v.z, v.w};
            short4v ph, pl;
#pragma unroll
            for (int c = 0; c < 4; ++c) {
                u16 h = f2bf(xs[c]);
                ph[c] = (short)h;
                pl[c] = (short)f2bf(xs[c] - bf2f(h));
            }
            *(short4v*)&oR_hi[(size_t)gr * H + h0] = ph;
            *(short4v*)&oR_lo[(size_t)gr * H + h0] = pl;
        }
        {   // transposed out
            int hh = t >> 2, jj = (t & 3) * 4;
            short4v th, tl;
#pragma unroll
            for (int r = 0; r < 4; ++r) {
                float x = sout[jj + r][hh];
                u16 h = f2bf(x);
                th[r] = (short)h;
                tl[r] = (short)f2bf(x - bf2f(h));
            }
            size_t o = (size_t)b * H * N + (size_t)hh * N + j0 + jj;
            *(short4v*)&oT_hi[o] = th;
            *(short4v*)&oT_lo[o] = tl;
        }
    } else {
        // ===== Phase D: hi = out@W1[:H], hj = out@W1[H:2H]  (K=128) ========
        acc = (f32x4){0.f, 0.f, 0.f, 0.f};
#pragma unroll
        for (int c = 0; c < 4; ++c) {
            short8 ah = *(const short8*)&sagg_hi[lrow][c * 32 + kg8];
            short8 al = *(const short8*)&sagg_lo[lrow][c * 32 + kg8];
            acc = __builtin_amdgcn_mfma_f32_16x16x32_bf16(ah, fd0[c], acc, 0, 0, 0);
            acc = __builtin_amdgcn_mfma_f32_16x16x32_bf16(ah, fd1[c], acc, 0, 0, 0);
            acc = __builtin_amdgcn_mfma_f32_16x16x32_bf16(al, fd0[c], acc, 0, 0, 0);
        }
#pragma unroll
        for (int r = 0; r < 4; ++r) sout[rb + r][colD] = acc[r];
        __syncthreads();
        int row = t >> 5, c0 = (t & 31) * 4;
        int gr = gb + j0 + row;
        float4 v = *(const float4*)&sout[row][c0];
        if (c0 < 64) *(float4*)&hi_out[(size_t)gr * FH + c0] = v;
        else         *(float4*)&hj_out[(size_t)gr * FH + (c0 - 64)] = v;
    }
}

// ---------------------------------------------------------------------------
// k_final: unchanged from R6. grid 2048, 256 thr.
__global__ __launch_bounds__(256) void k_final(
    const float* __restrict__ hi, const float* __restrict__ hj,
    const float* __restrict__ e0p, const float* __restrict__ e1p,
    const float* __restrict__ e2p, const float* __restrict__ temporal,
    const float* __restrict__ W1, const float* __restrict__ b1,
    const float* __restrict__ W2, const float* __restrict__ b2,
    float* __restrict__ flows) {
    __shared__ float his[8][FH];
    __shared__ float hjs[32][FH + 2];
    __shared__ float wr0[FH], wr1[FH], wr2[FH];
    __shared__ float wt0[FH], wt1[FH], wt2[FH], wt3[FH], bb[FH], w2s[FH];
    int blk = blockIdx.x;
    int jt = blk & 7, it = (blk >> 3) & 31, b = blk >> 8;
    int tid = threadIdx.x;
#pragma unroll
    for (int u = 0; u < 2; ++u) {
        int idx = u * 256 + tid;
        his[idx >> 6][idx & 63] = hi[((size_t)(b * N) + it * 8 + (idx >> 6)) * FH + (idx & 63)];
    }
#pragma unroll
    for (int u = 0; u < 8; ++u) {
        int idx = u * 256 + tid;
        hjs[idx >> 6][idx & 63] = hj[((size_t)(b * N) + jt * 32 + (idx >> 6)) * FH + (idx & 63)];
    }
    {
        int f = tid & 63, g = tid >> 6;
        if (g == 0) { wr0[f] = W1[(2 * H + 0) * FH + f]; wt0[f] = W1[(2 * H + 3) * FH + f]; bb[f] = b1[f]; }
        if (g == 1) { wr1[f] = W1[(2 * H + 1) * FH + f]; wt1[f] = W1[(2 * H + 4) * FH + f]; w2s[f] = W2[f]; }
        if (g == 2) { wr2[f] = W1[(2 * H + 2) * FH + f]; wt2[f] = W1[(2 * H + 5) * FH + f]; }
        if (g == 3) { wt3[f] = W1[(2 * H + 6) * FH + f]; }
    }
    __syncthreads();
    int ti = tid >> 5, tj = tid & 31;
    int i = it * 8 + ti, j = jt * 32 + tj;
    size_t pij = ((size_t)(b * N) + i) * N + j;
    float e0 = e0p[pij], e1 = e1p[pij], e2 = e2p[pij];
    float4 tf = *(const float4*)(temporal + pij * TD);
    float acc = 0.f;
#pragma unroll 8
    for (int f = 0; f < FH; ++f) {
        float v = his[ti][f] + hjs[tj][f] + bb[f]
                + e0 * wr0[f] + e1 * wr1[f] + e2 * wr2[f]
                + tf.x * wt0[f] + tf.y * wt1[f] + tf.z * wt2[f] + tf.w * wt3[f];
        acc += fmaxf(v, 0.f) * w2s[f];
    }
    flows[pij] = fmaxf(acc + b2[0], 0.f);
}

// ---------------------------------------------------------------------------
extern "C" void kernel_launch(void* const* d_in, const int* in_sizes, int n_in,
                              void* d_out, int out_size, void* d_ws, size_t ws_size,
                              hipStream_t stream) {
    const float* nf       = (const float*)d_in[0];
    const float* edge     = (const float*)d_in[1];
    const float* temporal = (const float*)d_in[2];
    const int*   adj      = (const int*)d_in[3];
    const float* W_emb    = (const float*)d_in[4];
    const float* b_emb    = (const float*)d_in[5];
    const float* msg_W    = (const float*)d_in[6];
    const float* msg_b    = (const float*)d_in[7];
    const float* upd_W    = (const float*)d_in[8];
    const float* upd_b    = (const float*)d_in[9];
    const float* W1       = (const float*)d_in[10];
    const float* b1       = (const float*)d_in[11];
    const float* W2       = (const float*)d_in[12];
    const float* b2       = (const float*)d_in[13];
    float* out = (float*)d_out;
    (void)in_sizes; (void)n_in; (void)out_size; (void)ws_size;

    char* p = (char*)d_ws;
    auto take = [&](size_t bytes) { char* r = p; p += (bytes + 255) & ~(size_t)255; return r; };
    float* deg   = (float*)take(256 * 4);
    float* ragg  = (float*)take((size_t)M * 3 * 4);
    float* e0p   = (float*)take((size_t)B * N * N * 4);
    float* e1p   = (float*)take((size_t)B * N * N * 4);
    float* e2p   = (float*)take((size_t)B * N * N * 4);
    float* rp0   = (float*)take((size_t)B * N * N * 4);
    float* rp1   = (float*)take((size_t)B * N * N * 4);
    float* rp2   = (float*)take((size_t)B * N * N * 4);
    float* hi    = (float*)take((size_t)M * FH * 4);
    float* hj    = (float*)take((size_t)M * FH * 4);
    u16* eRhA = (u16*)take((size_t)M * H * 2);
    u16* eRlA = (u16*)take((size_t)M * H * 2);
    u16* eThA = (u16*)take((size_t)M * H * 2);
    u16* eTlA = (u16*)take((size_t)M * H * 2);
    u16* eRhB = (u16*)take((size_t)M * H * 2);
    u16* eRlB = (u16*)take((size_t)M * H * 2);
    u16* eThB = (u16*)take((size_t)M * H * 2);
    u16* eTlB = (u16*)take((size_t)M * H * 2);
    u16* WeTh = (u16*)take(3 * 16384 * 2);
    u16* WeTl = (u16*)take(3 * 16384 * 2);
    u16* UwTh = (u16*)take(3 * 32768 * 2);
    u16* UwTl = (u16*)take(3 * 32768 * 2);
    u16* W1Th = (u16*)take(16384 * 2);
    u16* W1Tl = (u16*)take(16384 * 2);

    k_setup<<<3072, 256, 0, stream>>>(edge, adj, nf, W_emb, b_emb,
                                      msg_W, upd_W, W1,
                                      e0p, e1p, e2p, rp0, rp1, rp2, deg,
                                      WeTh, WeTl, UwTh, UwTl, W1Th, W1Tl,
                                      eRhA, eRlA, eThA, eTlA);

    const int mwS = (H + 3) * H;   // msg_W layer stride
    k_layer<true, false><<<128, 512, 0, stream>>>(
        eRhA, eRlA, eThA, eTlA, adj, rp0, rp1, rp2, ragg, deg,
        WeTh + 0 * 16384, WeTl + 0 * 16384, msg_W + 0 * mwS, msg_b + 0 * H,
        UwTh + 0 * 32768, UwTl + 0 * 32768, upd_b + 0 * H,
        eRhB, eRlB, eThB, eTlB, W1Th, W1Tl, hi, hj);
    k_layer<false, false><<<128, 512, 0, stream>>>(
        eRhB, eRlB, eThB, eTlB, adj, rp0, rp1, rp2, ragg, deg,
        WeTh + 1 * 16384, WeTl + 1 * 16384, msg_W + 1 * mwS, msg_b + 1 * H,
        UwTh + 1 * 32768, UwTl + 1 * 32768, upd_b + 1 * H,
        eRhA, eRlA, eThA, eTlA, W1Th, W1Tl, hi, hj);
    k_layer<false, true><<<128, 512, 0, stream>>>(
        eRhA, eRlA, eThA, eTlA, adj, rp0, rp1, rp2, ragg, deg,
        WeTh + 2 * 16384, WeTl + 2 * 16384, msg_W + 2 * mwS, msg_b + 2 * H,
        UwTh + 2 * 32768, UwTl + 2 * 32768, upd_b + 2 * H,
        eRhB, eRlB, eThB, eTlB, W1Th, W1Tl, hi, hj);

    k_final<<<2048, 256, 0, stream>>>(hi, hj, e0p, e1p, e2p, temporal,
                                      W1, b1, W2, b2, out);
}